// Round 8
// baseline (198.817 us; speedup 1.0000x reference)
//
#include <hip/hip_runtime.h>

#define N 8192
#define NCLS 81
#define PAD 300
#define NPANEL 16
#define PANW 512
#define JSPLIT 8

typedef unsigned long long u64;

#define WAITVM0() asm volatile("s_waitcnt vmcnt(0)" ::: "memory")

__device__ __forceinline__ void gload_lds16(const void* g, void* l) {
  __builtin_amdgcn_global_load_lds(
      (const __attribute__((address_space(1))) unsigned int*)g,
      (__attribute__((address_space(3))) unsigned int*)l, 16, 0, 0);
}

// ---------------- K1: decode, 8 lanes per row (coalesced 32B segments) ----------------
__global__ __launch_bounds__(256) void decode_kernel(
    const float* __restrict__ meta, const float* __restrict__ deltas,
    const float* __restrict__ proposals, const float* __restrict__ scores,
    float4* __restrict__ sel, u64* __restrict__ keys, int* __restrict__ rank) {
  int tid = threadIdx.x;
  int row = blockIdx.x * 32 + (tid >> 3);
  int sub = tid & 7;
  const float* srow = scores + (size_t)row * NCLS;
  float bs = -1e30f, ms = -1e30f;
  int best = 0;
  for (int c = sub; c < NCLS; c += 8) {
    float v = srow[c];
    if (v > bs) { bs = v; best = c; }  // ascending c: local first-max
    if (c > 0) ms = fmaxf(ms, v);
  }
  // 8-lane reduce: (max val, min class idx on ties) == global first-max
#pragma unroll
  for (int d = 1; d < 8; d <<= 1) {
    float ob = __shfl_xor(bs, d);
    int oi = __shfl_xor(best, d);
    float om = __shfl_xor(ms, d);
    if (ob > bs || (ob == bs && oi < best)) { bs = ob; best = oi; }
    ms = fmaxf(ms, om);
  }
  if (sub == 0) {
    float W = meta[1], sc = meta[2], H = meta[0];
    const float* p = proposals + row * 4;
    float x1 = p[0] / sc, y1 = p[1] / sc, x2 = p[2] / sc, y2 = p[3] / sc;
    float w = x2 - x1 + 1.0f, h = y2 - y1 + 1.0f;
    float cx = x1 + 0.5f * w, cy = y1 + 0.5f * h;
    float4 d4 = *(const float4*)(deltas + (size_t)row * (4 * NCLS) + best * 4);  // 16B aligned
    float pcx = d4.x * w + cx, pcy = d4.y * h + cy;
    float pw = expf(d4.z) * w, ph = expf(d4.w) * h;
    float lx = W - 1.0f, ly = H - 1.0f;
    float ox1 = fminf(fmaxf(pcx - 0.5f * pw, 0.0f), lx);
    float oy1 = fminf(fmaxf(pcy - 0.5f * ph, 0.0f), ly);
    float ox2 = fminf(fmaxf(pcx + 0.5f * pw, 0.0f), lx);
    float oy2 = fminf(fmaxf(pcy + 0.5f * ph, 0.0f), ly);
    sel[row] = make_float4(ox1, oy1, ox2, oy2);
    keys[row] = ((u64)(~__float_as_uint(ms)) << 32) | (unsigned)row;
    rank[row] = 0;
  }
}

// ---------------- K2a: brute-force rank (stable sort of unique keys) ----------------
__global__ __launch_bounds__(256) void rank_kernel(
    const u64* __restrict__ keys, int* __restrict__ rank) {
  int i = blockIdx.x * 256 + threadIdx.x;
  u64 ki = keys[i];
  int j0 = blockIdx.y * (N / JSPLIT);
  int c = 0;
#pragma unroll 8
  for (int j = j0; j < j0 + N / JSPLIT; ++j) c += (keys[j] < ki);
  atomicAdd(&rank[i], c);
}

// ---------------- K2b: scatter into sorted order ----------------
__global__ __launch_bounds__(256) void scatter_kernel(
    const int* __restrict__ rank, const float4* __restrict__ sel,
    int* __restrict__ sortedIdx, float4* __restrict__ sortedBoxes) {
  int i = blockIdx.x * 256 + threadIdx.x;
  int r = rank[i];
  sortedIdx[r] = i;
  sortedBoxes[r] = sel[i];
}

// ---------------- K3: suppression bitmask, ROW-MAJOR, upper triangle only ------
// 4 row-blocks per dispatch block, cbox reused. Lower-tri words stay poison —
// consumers provably never read them (same argument as R6, re-verified for the
// staged fold: poison lands at col-blocks <= current panel, never re-read).
__global__ __launch_bounds__(64) void mask_kernel(
    const float4* __restrict__ boxes, u64* __restrict__ mask) {
  int cb = blockIdx.x, rbq = blockIdx.y;
  if (cb < 4 * rbq) return;  // whole block strictly lower-tri
  __shared__ float4 cbox[64];
  cbox[threadIdx.x] = boxes[cb * 64 + threadIdx.x];
  __syncthreads();
#pragma unroll
  for (int k = 0; k < 4; ++k) {
    int rb = 4 * rbq + k;
    if (cb < rb) break;
    int r = rb * 64 + threadIdx.x;
    float4 bi = boxes[r];
    float areaA = fmaxf(bi.z - bi.x, 0.0f) * fmaxf(bi.w - bi.y, 0.0f);
    u64 bits = 0ull;
#pragma unroll 8
    for (int c = 0; c < 64; ++c) {
      int j = cb * 64 + c;
      float4 bj = cbox[c];
      float areaB = fmaxf(bj.z - bj.x, 0.0f) * fmaxf(bj.w - bj.y, 0.0f);
      float lxv = fmaxf(bi.x, bj.x), lyv = fmaxf(bi.y, bj.y);
      float rxv = fminf(bi.z, bj.z), ryv = fminf(bi.w, bj.w);
      float iw = fmaxf(rxv - lxv, 0.0f), ih = fmaxf(ryv - lyv, 0.0f);
      float inter = iw * ih;
      float u = areaA + areaB - inter + 1e-8f;
      float sA = inter * 33554432.0f;  // * 2^25, exact
      float sB = u * 16777216.0f;      // * 2^24, exact
      bool sup = ((sA - sB) - u > 0.0f);  // == RN(inter/u) > 0.5, bit-exact
      if (j > r && sup) bits |= (1ull << c);
    }
    mask[(size_t)r * 128 + cb] = bits;
  }
}

// ---------------- K4: greedy scan, 2 waves (scan + prefetcher) ----------------
// Wave 0: pure LDS+VALU hot loop (2-way spec, reg-resident panel words). Never
// issues global_load_lds -> no compiler vmcnt(0) stalls (R5 lesson).
// Wave 1: owns ALL global_load_lds — slab prefetch + kept-row staging into a
// 32-slot LDS ring, 8-row batched drain/publish rounds (per-wave vmcnt).
// Handshake: ctl[0] pubScan = done<<31|final<<30|cnt<<16|gi; ctl[1] foldedCnt;
// ctl[2] readyCnt. Window 32; wave0 flushes at backlog 32 (checked after every
// keep, so panel-end backlog <= 31 => wave1 can always finish => no deadlock).
__global__ __launch_bounds__(128) void nms_scan_kernel(
    const u64* __restrict__ mask, int* __restrict__ kept, int* __restrict__ num_kept) {
  __shared__ u64 slab[2][PANW * 8];  // 64 KiB double-buffered diagonal slabs
  __shared__ u64 stage[32 * 128];    // 32 KiB ring: staged full kept rows
  __shared__ int keptGi[PAD];
  __shared__ unsigned ctl[4];
  volatile unsigned* vctl = ctl;
  volatile int* vkept = keptGi;
  const char* mb = (const char*)mask;
  int tid = threadIdx.x;
  int lane = tid & 63;

  if (tid == 0) { ctl[0] = 0; ctl[1] = 0; ctl[2] = 0; }

  if (tid >= 64) {
    // ================= wave 1: prefetcher =================
    // slab for panel 0
    for (int it = 0; it < 32; ++it)
      gload_lds16(mb + (size_t)(it * 16 + (lane >> 2)) * 1024 + (lane & 3) * 16,
                  &slab[0][0] + it * 128);
    unsigned issued = 0;
    bool fin = false;
    for (int p = 0;; ++p) {
      __syncthreads();  // B0
      if (p < NPANEL - 1) {
        int q = p + 1;
        const char* sb = mb + (size_t)(q * PANW) * 1024 + (size_t)q * 64;
        u64* dst = &slab[q & 1][0];
        for (int it = 0; it < 32; ++it)
          gload_lds16(sb + (size_t)(it * 16 + (lane >> 2)) * 1024 + (lane & 3) * 16,
                      dst + it * 128);
      }
      while (true) {
        unsigned pub = vctl[0];          // vmcnt==0 at all these reads (post-drain)
        bool done = (pub >> 31) & 1;
        fin = (pub >> 30) & 1;
        unsigned seen = (pub >> 16) & 0x3FF;
        if (done && fin) break;          // final: stop issuing, outputs are done
        unsigned folded = vctl[1];
        unsigned avail = seen - issued;
        unsigned room = 32 - (issued - folded);
        if (avail > room) avail = room;
        if (avail > 8) avail = 8;
        if (avail > 0) {
          // ALL gi reads BEFORE any gload_lds (keeps LDS reads out of vm-shadow)
          int g0 = 0, g1 = 0, g2 = 0, g3 = 0, g4 = 0, g5 = 0, g6 = 0, g7 = 0;
          if (avail > 0) g0 = vkept[issued + 0];
          if (avail > 1) g1 = vkept[issued + 1];
          if (avail > 2) g2 = vkept[issued + 2];
          if (avail > 3) g3 = vkept[issued + 3];
          if (avail > 4) g4 = vkept[issued + 4];
          if (avail > 5) g5 = vkept[issued + 5];
          if (avail > 6) g6 = vkept[issued + 6];
          if (avail > 7) g7 = vkept[issued + 7];
          if (avail > 0) gload_lds16(mb + (size_t)g0 * 1024 + lane * 16, stage + ((issued + 0) & 31) * 128);
          if (avail > 1) gload_lds16(mb + (size_t)g1 * 1024 + lane * 16, stage + ((issued + 1) & 31) * 128);
          if (avail > 2) gload_lds16(mb + (size_t)g2 * 1024 + lane * 16, stage + ((issued + 2) & 31) * 128);
          if (avail > 3) gload_lds16(mb + (size_t)g3 * 1024 + lane * 16, stage + ((issued + 3) & 31) * 128);
          if (avail > 4) gload_lds16(mb + (size_t)g4 * 1024 + lane * 16, stage + ((issued + 4) & 31) * 128);
          if (avail > 5) gload_lds16(mb + (size_t)g5 * 1024 + lane * 16, stage + ((issued + 5) & 31) * 128);
          if (avail > 6) gload_lds16(mb + (size_t)g6 * 1024 + lane * 16, stage + ((issued + 6) & 31) * 128);
          if (avail > 7) gload_lds16(mb + (size_t)g7 * 1024 + lane * 16, stage + ((issued + 7) & 31) * 128);
          issued += avail;
          WAITVM0();
          if (lane == 0) vctl[2] = issued;
        } else if (done && issued >= seen) {
          break;
        } else {
          __builtin_amdgcn_s_sleep(1);
        }
      }
      __syncthreads();  // B1 (drains any outstanding vm ops of this wave)
      if (fin) break;
    }
    return;
  }

  // ================= wave 0: greedy scan =================
  u64 own0 = 0ull, own1 = 0ull;  // lane owns global remv words 2l, 2l+1
  int cnt = 0, folded = 0;
  bool finished = false;

#define PUBLISH_KEEP(GI)                                                      \
  do {                                                                        \
    if (lane == 0) {                                                          \
      vkept[cnt] = (GI);                                                      \
      vctl[0] = ((unsigned)(cnt + 1) << 16) | (unsigned)(GI);                 \
    }                                                                         \
    cnt++;                                                                    \
  } while (0)

#define FLUSH32()                                                             \
  do {                                                                        \
    if (cnt - folded >= 32) {                                                 \
      unsigned tgt = (unsigned)folded + 32;                                   \
      while (vctl[2] < tgt) __builtin_amdgcn_s_sleep(1);                      \
      for (int t = 0; t < 32; ++t) {                                          \
        ulonglong2 v = ((const ulonglong2*)(stage + ((folded + t) & 31) * 128))[lane]; \
        own0 |= v.x;                                                          \
        own1 |= v.y;                                                          \
      }                                                                       \
      folded += 32;                                                           \
      if (lane == 0) vctl[1] = (unsigned)folded;                              \
    }                                                                         \
  } while (0)

  for (int p = 0;; ++p) {
    int base = p * PANW;
    const u64* sl = &slab[p & 1][0];
    __syncthreads();  // B0: slab p ready (wave1's prior barrier drained it)

    u64 rv0 = __shfl(own0, 4 * p), rv1 = __shfl(own1, 4 * p);
    u64 rv2 = __shfl(own0, 4 * p + 1), rv3 = __shfl(own1, 4 * p + 1);
    u64 rv4 = __shfl(own0, 4 * p + 2), rv5 = __shfl(own1, 4 * p + 2);
    u64 rv6 = __shfl(own0, 4 * p + 3), rv7 = __shfl(own1, 4 * p + 3);
    int w = 0;
    u64 cur = rv0;

    while (cnt < PAD) {
      u64 inv = ~cur;
      if (inv == 0ull) {
        if (++w == 8) break;
        cur = (w == 1) ? rv1 : (w == 2) ? rv2 : (w == 3) ? rv3 : (w == 4) ? rv4
            : (w == 5) ? rv5 : (w == 6) ? rv6 : rv7;
        continue;
      }
      int b1 = __ffsll(inv) - 1;
      u64 inv2 = inv & (inv - 1);
      int li1 = (w << 6) + b1;
      int b2 = inv2 ? (__ffsll(inv2) - 1) : -1;
      int li2 = (b2 >= 0) ? ((w << 6) + b2) : li1;
      const u64* rA = sl + li1 * 8;
      const u64* rB = sl + li2 * 8;
      u64 mA = rA[w];  // dependent hop
      u64 mB = rB[w];  // speculative, same latency window
      ulonglong2 a0 = ((const ulonglong2*)rA)[0], a1 = ((const ulonglong2*)rA)[1];
      ulonglong2 a2 = ((const ulonglong2*)rA)[2], a3 = ((const ulonglong2*)rA)[3];
      PUBLISH_KEEP(base + li1);
      cur |= mA | (1ull << b1);
      rv0 |= a0.x; rv1 |= a0.y; rv2 |= a1.x; rv3 |= a1.y;
      rv4 |= a2.x; rv5 |= a2.y; rv6 |= a3.x; rv7 |= a3.y;
      if (cnt >= PAD) break;
      FLUSH32();
      if (b2 >= 0 && !((mA >> b2) & 1ull)) {  // speculation success
        ulonglong2 c0 = ((const ulonglong2*)rB)[0], c1 = ((const ulonglong2*)rB)[1];
        ulonglong2 c2 = ((const ulonglong2*)rB)[2], c3 = ((const ulonglong2*)rB)[3];
        PUBLISH_KEEP(base + li2);
        cur |= mB | (1ull << b2);
        rv0 |= c0.x; rv1 |= c0.y; rv2 |= c1.x; rv3 |= c1.y;
        rv4 |= c2.x; rv5 |= c2.y; rv6 |= c3.x; rv7 |= c3.y;
        if (cnt >= PAD) break;
        FLUSH32();
      }
    }

    finished = (cnt >= PAD) || (p == NPANEL - 1);
    if (lane == 0)
      vctl[0] = 0x80000000u | (finished ? 0x40000000u : 0u) | ((unsigned)cnt << 16);
    __syncthreads();  // B1
    if (finished) break;

    // panel-exit fold: remaining staged rows (backlog <= 31, all issued by wave1
    // pre-B1; barrier guarantees data landed in LDS)
    for (int t = folded; t < cnt; ++t) {
      ulonglong2 v = ((const ulonglong2*)(stage + (t & 31) * 128))[lane];
      own0 |= v.x;
      own1 |= v.y;
    }
    folded = cnt;
    if (lane == 0) { vctl[1] = (unsigned)folded; vctl[0] = (unsigned)cnt << 16; }
  }

  // epilogue
  for (int k = lane; k < cnt; k += 64) kept[k] = keptGi[k];
  if (lane == 0) *num_kept = cnt;
#undef PUBLISH_KEEP
#undef FLUSH32
}

// ---------------- K5: gather outputs ----------------
__global__ __launch_bounds__(128) void gather_kernel(
    const int* __restrict__ kept, const int* __restrict__ num_kept_p,
    const int* __restrict__ sortedIdx, const float4* __restrict__ sortedBoxes,
    const float* __restrict__ scores, float* __restrict__ out) {
  int r = blockIdx.x;  // 0..299
  int t = threadIdx.x;
  float* boxes_out = out;             // (300,4)
  float* scores_out = out + PAD * 4;  // (300,81)
  int nk = *num_kept_p;
  bool valid = r < nk;
  int pos = valid ? kept[r] : 0;
  if (t < NCLS) {
    int orig = sortedIdx[pos];
    scores_out[(size_t)r * NCLS + t] = valid ? scores[(size_t)orig * NCLS + t] : 0.0f;
  }
  if (t == 96) {
    float4 b = sortedBoxes[pos];
    if (!valid) b = make_float4(0.f, 0.f, 0.f, 0.f);
    ((float4*)boxes_out)[r] = b;
  }
}

extern "C" void kernel_launch(void* const* d_in, const int* in_sizes, int n_in,
                              void* d_out, int out_size, void* d_ws, size_t ws_size,
                              hipStream_t stream) {
  const float* meta = (const float*)d_in[0];
  const float* deltas = (const float*)d_in[1];
  const float* proposals = (const float*)d_in[2];
  const float* scores = (const float*)d_in[3];
  float* out = (float*)d_out;
  char* ws = (char*)d_ws;

  float4* sel = (float4*)(ws + 0);               // 131072 B
  u64* keys = (u64*)(ws + 131072);               // 65536 B
  int* rank = (int*)(ws + 196608);               // 32768 B
  int* sortedIdx = (int*)(ws + 229376);          // 32768 B
  float4* sortedBoxes = (float4*)(ws + 262144);  // 131072 B
  int* kept = (int*)(ws + 393216);               // 1200 B
  int* num_kept = (int*)(ws + 395264);           // 4 B
  u64* mask = (u64*)(ws + 409600);               // 8 MiB row-major

  decode_kernel<<<N / 32, 256, 0, stream>>>(meta, deltas, proposals, scores, sel, keys, rank);
  rank_kernel<<<dim3(N / 256, JSPLIT), 256, 0, stream>>>(keys, rank);
  scatter_kernel<<<N / 256, 256, 0, stream>>>(rank, sel, sortedIdx, sortedBoxes);
  mask_kernel<<<dim3(N / 64, N / 256), 64, 0, stream>>>(sortedBoxes, mask);
  nms_scan_kernel<<<1, 128, 0, stream>>>(mask, kept, num_kept);
  gather_kernel<<<PAD, 128, 0, stream>>>(kept, num_kept, sortedIdx, sortedBoxes, scores, out);
}

// Round 9
// 122.377 us; speedup vs baseline: 1.6246x; 1.6246x over previous
//
#include <hip/hip_runtime.h>

#define N 8192
#define NCLS 81
#define PAD 300
#define NPANEL 16
#define PANW 512

typedef unsigned long long u64;

// ---------------- K1: decode, 8 lanes per row (coalesced 32B segments) ----------------
__global__ __launch_bounds__(256) void decode_kernel(
    const float* __restrict__ meta, const float* __restrict__ deltas,
    const float* __restrict__ proposals, const float* __restrict__ scores,
    float4* __restrict__ sel, u64* __restrict__ keys, int* __restrict__ rank) {
  int tid = threadIdx.x;
  int row = blockIdx.x * 32 + (tid >> 3);
  int sub = tid & 7;
  const float* srow = scores + (size_t)row * NCLS;
  float bs = -1e30f, ms = -1e30f;
  int best = 0;
  for (int c = sub; c < NCLS; c += 8) {
    float v = srow[c];
    if (v > bs) { bs = v; best = c; }  // ascending c: local first-max
    if (c > 0) ms = fmaxf(ms, v);
  }
  // 8-lane reduce: (max val, min class idx on ties) == global first-max (jnp.argmax)
#pragma unroll
  for (int d = 1; d < 8; d <<= 1) {
    float ob = __shfl_xor(bs, d);
    int oi = __shfl_xor(best, d);
    float om = __shfl_xor(ms, d);
    if (ob > bs || (ob == bs && oi < best)) { bs = ob; best = oi; }
    ms = fmaxf(ms, om);
  }
  if (sub == 0) {
    float W = meta[1], sc = meta[2], H = meta[0];
    const float* p = proposals + row * 4;
    float x1 = p[0] / sc, y1 = p[1] / sc, x2 = p[2] / sc, y2 = p[3] / sc;
    float w = x2 - x1 + 1.0f, h = y2 - y1 + 1.0f;
    float cx = x1 + 0.5f * w, cy = y1 + 0.5f * h;
    float4 d4 = *(const float4*)(deltas + (size_t)row * (4 * NCLS) + best * 4);  // 16B aligned
    float pcx = d4.x * w + cx, pcy = d4.y * h + cy;
    float pw = expf(d4.z) * w, ph = expf(d4.w) * h;
    float lx = W - 1.0f, ly = H - 1.0f;
    float ox1 = fminf(fmaxf(pcx - 0.5f * pw, 0.0f), lx);
    float oy1 = fminf(fmaxf(pcy - 0.5f * ph, 0.0f), ly);
    float ox2 = fminf(fmaxf(pcx + 0.5f * pw, 0.0f), lx);
    float oy2 = fminf(fmaxf(pcy + 0.5f * ph, 0.0f), ly);
    sel[row] = make_float4(ox1, oy1, ox2, oy2);
    keys[row] = ((u64)(~__float_as_uint(ms)) << 32) | (unsigned)row;
    rank[row] = 0;
  }
}

// ---------------- K2a: brute-force rank, LDS-tiled (stable sort of unique keys) ------
// grid (32,32): block x owns 256 i's, block y owns a 256-key j-tile staged in LDS.
// Broadcast ds_read per compare (throughput ~5.8cy); 4 blocks/CU occupancy.
// atomicAdd int sum: associative -> deterministic.
__global__ __launch_bounds__(256) void rank_kernel(
    const u64* __restrict__ keys, int* __restrict__ rank) {
  __shared__ u64 kt[256];
  int tid = threadIdx.x;
  int i = blockIdx.x * 256 + tid;
  kt[tid] = keys[blockIdx.y * 256 + tid];
  u64 ki = keys[i];
  __syncthreads();
  int c = 0;
#pragma unroll 8
  for (int t = 0; t < 256; ++t) c += (kt[t] < ki);
  atomicAdd(&rank[i], c);
}

// ---------------- K2b: scatter into sorted order ----------------
__global__ __launch_bounds__(256) void scatter_kernel(
    const int* __restrict__ rank, const float4* __restrict__ sel,
    int* __restrict__ sortedIdx, float4* __restrict__ sortedBoxes) {
  int i = blockIdx.x * 256 + threadIdx.x;
  int r = rank[i];
  sortedIdx[r] = i;
  sortedBoxes[r] = sel[i];
}

// ---------------- K3: suppression bitmask, ROW-MAJOR, upper triangle only ------
// 4 row-blocks per dispatch block, cbox reused. Lower-tri words stay poison —
// consumers provably never read them (scan reads diagonal-slab words only at
// bits >= scan position; fold poison lands at col-blocks <= current panel).
// Division removed bit-exactly: RN(a/u) > 0.5  <=>  a*2^25 - u*2^24 - u > 0.
__global__ __launch_bounds__(64) void mask_kernel(
    const float4* __restrict__ boxes, u64* __restrict__ mask) {
  int cb = blockIdx.x, rbq = blockIdx.y;
  if (cb < 4 * rbq) return;  // whole block strictly lower-tri
  __shared__ float4 cbox[64];
  cbox[threadIdx.x] = boxes[cb * 64 + threadIdx.x];
  __syncthreads();
#pragma unroll
  for (int k = 0; k < 4; ++k) {
    int rb = 4 * rbq + k;
    if (cb < rb) break;
    int r = rb * 64 + threadIdx.x;
    float4 bi = boxes[r];
    float areaA = fmaxf(bi.z - bi.x, 0.0f) * fmaxf(bi.w - bi.y, 0.0f);
    u64 bits = 0ull;
#pragma unroll 8
    for (int c = 0; c < 64; ++c) {
      int j = cb * 64 + c;
      float4 bj = cbox[c];
      float areaB = fmaxf(bj.z - bj.x, 0.0f) * fmaxf(bj.w - bj.y, 0.0f);
      float lxv = fmaxf(bi.x, bj.x), lyv = fmaxf(bi.y, bj.y);
      float rxv = fminf(bi.z, bj.z), ryv = fminf(bi.w, bj.w);
      float iw = fmaxf(rxv - lxv, 0.0f), ih = fmaxf(ryv - lyv, 0.0f);
      float inter = iw * ih;
      float u = areaA + areaB - inter + 1e-8f;
      float sA = inter * 33554432.0f;  // * 2^25, exact
      float sB = u * 16777216.0f;      // * 2^24, exact
      bool sup = ((sA - sB) - u > 0.0f);  // == RN(inter/u) > 0.5, bit-exact
      if (j > r && sup) bits |= (1ull << c);
    }
    mask[(size_t)r * 128 + cb] = bits;
  }
}

// ---------------- K4: serial greedy scan (R6 proven form) ----------------
// No VM ops inside the scan loop (R5/R7 lesson: any outstanding global_load_lds
// or cross-wave handshake in the keep chain costs ~900cy-µs per keep).
// Panel words in named regs rv0..rv7; 2-way speculative keeps.
__global__ __launch_bounds__(64) void nms_scan_kernel(
    const u64* __restrict__ mask, int* __restrict__ kept, int* __restrict__ num_kept) {
  __shared__ u64 slab[2][PANW * 8];  // 2 x 32 KiB double-buffered diagonal slabs
  __shared__ int keptLi[PAD];        // in-panel indices, indexed by global cnt
  int lane = threadIdx.x;
  u64 own0 = 0ull, own1 = 0ull;      // lane owns global remv words 2l, 2l+1
  int cnt = 0;
  const char* mb = (const char*)mask;

  // slab copy for panel 0: rows [0,512) x words [0,8)
#pragma unroll
  for (int it = 0; it < 32; ++it) {
    const char* g = mb + (size_t)(it * 16 + (lane >> 2)) * 1024 + (lane & 3) * 16;
    __builtin_amdgcn_global_load_lds(
        (const __attribute__((address_space(1))) unsigned int*)g,
        (__attribute__((address_space(3))) unsigned int*)(&slab[0][0] + it * 128), 16, 0, 0);
  }

  for (int p = 0; p < NPANEL; ++p) {
    int base = p * PANW;
    const u64* sl = &slab[p & 1][0];
    __syncthreads();  // drains slab copy (vmcnt0) — no VM ops live during scan

    // panel entry: replicate remv words 8p..8p+7 into named regs
    u64 rv0 = __shfl(own0, 4 * p), rv1 = __shfl(own1, 4 * p);
    u64 rv2 = __shfl(own0, 4 * p + 1), rv3 = __shfl(own1, 4 * p + 1);
    u64 rv4 = __shfl(own0, 4 * p + 2), rv5 = __shfl(own1, 4 * p + 2);
    u64 rv6 = __shfl(own0, 4 * p + 3), rv7 = __shfl(own1, 4 * p + 3);
    int w = 0;
    u64 cur = rv0;
    int panelFirst = cnt;

    while (cnt < PAD) {
      u64 inv = ~cur;
      if (inv == 0ull) {  // word exhausted
        if (++w == 8) break;
        cur = (w == 1) ? rv1 : (w == 2) ? rv2 : (w == 3) ? rv3 : (w == 4) ? rv4
            : (w == 5) ? rv5 : (w == 6) ? rv6 : rv7;
        continue;
      }
      int b1 = __ffsll(inv) - 1;
      u64 inv2 = inv & (inv - 1);
      int li1 = (w << 6) + b1;
      int b2 = inv2 ? (__ffsll(inv2) - 1) : -1;
      int li2 = inv2 ? ((w << 6) + b2) : li1;
      const u64* rA = sl + li1 * 8;
      const u64* rB = sl + li2 * 8;
      u64 mA = rA[w];  // dependent hop (chain)
      u64 mB = rB[w];  // speculative, same latency window
      ulonglong2 a0 = ((const ulonglong2*)rA)[0], a1 = ((const ulonglong2*)rA)[1];
      ulonglong2 a2 = ((const ulonglong2*)rA)[2], a3 = ((const ulonglong2*)rA)[3];
      if (lane == 0) kept[cnt] = base + li1;
      keptLi[cnt] = li1;
      cnt++;
      cur |= mA | (1ull << b1);
      rv0 |= a0.x; rv1 |= a0.y; rv2 |= a1.x; rv3 |= a1.y;
      rv4 |= a2.x; rv5 |= a2.y; rv6 |= a3.x; rv7 |= a3.y;
      if (b2 >= 0 && cnt < PAD && !((mA >> b2) & 1ull)) {  // speculation success
        ulonglong2 c0 = ((const ulonglong2*)rB)[0], c1 = ((const ulonglong2*)rB)[1];
        ulonglong2 c2 = ((const ulonglong2*)rB)[2], c3 = ((const ulonglong2*)rB)[3];
        if (lane == 0) kept[cnt] = base + li2;
        keptLi[cnt] = li2;
        cnt++;
        cur |= mB | (1ull << b2);
        rv0 |= c0.x; rv1 |= c0.y; rv2 |= c1.x; rv3 |= c1.y;
        rv4 |= c2.x; rv5 |= c2.y; rv6 |= c3.x; rv7 |= c3.y;
      }
    }
    if (cnt >= PAD || p == NPANEL - 1) break;

    // issue slab copy for panel p+1 (overlaps the fold below; drained at top barrier)
    {
      u64* dst = &slab[(p + 1) & 1][0];
      const char* srcB = mb + (size_t)(base + PANW) * 1024 + (size_t)(p + 1) * 64;
#pragma unroll
      for (int it = 0; it < 32; ++it) {
        const char* g = srcB + (size_t)(it * 16 + (lane >> 2)) * 1024 + (lane & 3) * 16;
        __builtin_amdgcn_global_load_lds(
            (const __attribute__((address_space(1))) unsigned int*)g,
            (__attribute__((address_space(3))) unsigned int*)(dst + it * 128), 16, 0, 0);
      }
    }

    // panel-exit fold: OR this panel's keeps' FULL 1KB rows into owned words.
    // Row-major: lane reads 16B at row + lane*16 == words 2l, 2l+1. 8-batched ILP.
    int nk = cnt - panelFirst;
    for (int t0 = 0; t0 < nk; t0 += 8) {
      int m = nk - t0;
      ulonglong2 v0, v1, v2, v3, v4, v5, v6, v7;
#define ROWP(t) (((const ulonglong2*)(mask + (size_t)(base + keptLi[panelFirst + (t)]) * 128))[lane])
      if (0 < m) v0 = ROWP(t0 + 0);
      if (1 < m) v1 = ROWP(t0 + 1);
      if (2 < m) v2 = ROWP(t0 + 2);
      if (3 < m) v3 = ROWP(t0 + 3);
      if (4 < m) v4 = ROWP(t0 + 4);
      if (5 < m) v5 = ROWP(t0 + 5);
      if (6 < m) v6 = ROWP(t0 + 6);
      if (7 < m) v7 = ROWP(t0 + 7);
#undef ROWP
      if (0 < m) { own0 |= v0.x; own1 |= v0.y; }
      if (1 < m) { own0 |= v1.x; own1 |= v1.y; }
      if (2 < m) { own0 |= v2.x; own1 |= v2.y; }
      if (3 < m) { own0 |= v3.x; own1 |= v3.y; }
      if (4 < m) { own0 |= v4.x; own1 |= v4.y; }
      if (5 < m) { own0 |= v5.x; own1 |= v5.y; }
      if (6 < m) { own0 |= v6.x; own1 |= v6.y; }
      if (7 < m) { own0 |= v7.x; own1 |= v7.y; }
    }
  }
  if (lane == 0) *num_kept = cnt;
}

// ---------------- K5: gather outputs ----------------
__global__ __launch_bounds__(128) void gather_kernel(
    const int* __restrict__ kept, const int* __restrict__ num_kept_p,
    const int* __restrict__ sortedIdx, const float4* __restrict__ sortedBoxes,
    const float* __restrict__ scores, float* __restrict__ out) {
  int r = blockIdx.x;  // 0..299
  int t = threadIdx.x;
  float* boxes_out = out;             // (300,4)
  float* scores_out = out + PAD * 4;  // (300,81)
  int nk = *num_kept_p;
  bool valid = r < nk;
  int pos = valid ? kept[r] : 0;
  if (t < NCLS) {
    int orig = sortedIdx[pos];
    scores_out[(size_t)r * NCLS + t] = valid ? scores[(size_t)orig * NCLS + t] : 0.0f;
  }
  if (t == 96) {
    float4 b = sortedBoxes[pos];
    if (!valid) b = make_float4(0.f, 0.f, 0.f, 0.f);
    ((float4*)boxes_out)[r] = b;
  }
}

extern "C" void kernel_launch(void* const* d_in, const int* in_sizes, int n_in,
                              void* d_out, int out_size, void* d_ws, size_t ws_size,
                              hipStream_t stream) {
  const float* meta = (const float*)d_in[0];
  const float* deltas = (const float*)d_in[1];
  const float* proposals = (const float*)d_in[2];
  const float* scores = (const float*)d_in[3];
  float* out = (float*)d_out;
  char* ws = (char*)d_ws;

  float4* sel = (float4*)(ws + 0);               // 131072 B
  u64* keys = (u64*)(ws + 131072);               // 65536 B
  int* rank = (int*)(ws + 196608);               // 32768 B
  int* sortedIdx = (int*)(ws + 229376);          // 32768 B
  float4* sortedBoxes = (float4*)(ws + 262144);  // 131072 B
  int* kept = (int*)(ws + 393216);               // 1200 B
  int* num_kept = (int*)(ws + 395264);           // 4 B
  u64* mask = (u64*)(ws + 409600);               // 8 MiB row-major

  decode_kernel<<<N / 32, 256, 0, stream>>>(meta, deltas, proposals, scores, sel, keys, rank);
  rank_kernel<<<dim3(N / 256, N / 256), 256, 0, stream>>>(keys, rank);
  scatter_kernel<<<N / 256, 256, 0, stream>>>(rank, sel, sortedIdx, sortedBoxes);
  mask_kernel<<<dim3(N / 64, N / 256), 64, 0, stream>>>(sortedBoxes, mask);
  nms_scan_kernel<<<1, 64, 0, stream>>>(mask, kept, num_kept);
  gather_kernel<<<PAD, 128, 0, stream>>>(kept, num_kept, sortedIdx, sortedBoxes, scores, out);
}

// Round 10
// 118.928 us; speedup vs baseline: 1.6717x; 1.0290x over previous
//
#include <hip/hip_runtime.h>

#define N 8192
#define NCLS 81
#define PAD 300
#define NPANEL 16
#define PANW 512

typedef unsigned long long u64;

// ---------------- K1: decode, 8 lanes per row (coalesced 32B segments) ----------------
__global__ __launch_bounds__(256) void decode_kernel(
    const float* __restrict__ meta, const float* __restrict__ deltas,
    const float* __restrict__ proposals, const float* __restrict__ scores,
    float4* __restrict__ sel, u64* __restrict__ keys, int* __restrict__ rank) {
  int tid = threadIdx.x;
  int row = blockIdx.x * 32 + (tid >> 3);
  int sub = tid & 7;
  const float* srow = scores + (size_t)row * NCLS;
  float bs = -1e30f, ms = -1e30f;
  int best = 0;
  for (int c = sub; c < NCLS; c += 8) {
    float v = srow[c];
    if (v > bs) { bs = v; best = c; }  // ascending c: local first-max
    if (c > 0) ms = fmaxf(ms, v);
  }
  // 8-lane reduce: (max val, min class idx on ties) == global first-max (jnp.argmax)
#pragma unroll
  for (int d = 1; d < 8; d <<= 1) {
    float ob = __shfl_xor(bs, d);
    int oi = __shfl_xor(best, d);
    float om = __shfl_xor(ms, d);
    if (ob > bs || (ob == bs && oi < best)) { bs = ob; best = oi; }
    ms = fmaxf(ms, om);
  }
  if (sub == 0) {
    float W = meta[1], sc = meta[2], H = meta[0];
    const float* p = proposals + row * 4;
    float x1 = p[0] / sc, y1 = p[1] / sc, x2 = p[2] / sc, y2 = p[3] / sc;
    float w = x2 - x1 + 1.0f, h = y2 - y1 + 1.0f;
    float cx = x1 + 0.5f * w, cy = y1 + 0.5f * h;
    float4 d4 = *(const float4*)(deltas + (size_t)row * (4 * NCLS) + best * 4);  // 16B aligned
    float pcx = d4.x * w + cx, pcy = d4.y * h + cy;
    float pw = expf(d4.z) * w, ph = expf(d4.w) * h;
    float lx = W - 1.0f, ly = H - 1.0f;
    float ox1 = fminf(fmaxf(pcx - 0.5f * pw, 0.0f), lx);
    float oy1 = fminf(fmaxf(pcy - 0.5f * ph, 0.0f), ly);
    float ox2 = fminf(fmaxf(pcx + 0.5f * pw, 0.0f), lx);
    float oy2 = fminf(fmaxf(pcy + 0.5f * ph, 0.0f), ly);
    sel[row] = make_float4(ox1, oy1, ox2, oy2);
    keys[row] = ((u64)(~__float_as_uint(ms)) << 32) | (unsigned)row;
    rank[row] = 0;
  }
}

// ---------------- K2a: brute-force rank, LDS-tiled (stable sort of unique keys) ------
__global__ __launch_bounds__(256) void rank_kernel(
    const u64* __restrict__ keys, int* __restrict__ rank) {
  __shared__ u64 kt[256];
  int tid = threadIdx.x;
  int i = blockIdx.x * 256 + tid;
  kt[tid] = keys[blockIdx.y * 256 + tid];
  u64 ki = keys[i];
  __syncthreads();
  int c = 0;
#pragma unroll 8
  for (int t = 0; t < 256; ++t) c += (kt[t] < ki);
  atomicAdd(&rank[i], c);
}

// ---------------- K2b: scatter into sorted order ----------------
__global__ __launch_bounds__(256) void scatter_kernel(
    const int* __restrict__ rank, const float4* __restrict__ sel,
    int* __restrict__ sortedIdx, float4* __restrict__ sortedBoxes) {
  int i = blockIdx.x * 256 + threadIdx.x;
  int r = rank[i];
  sortedIdx[r] = i;
  sortedBoxes[r] = sel[i];
}

// ---------------- K3: suppression bitmask, ROW-MAJOR, line-coherent writes ------
// Block (q, ry): rows [256ry, 256ry+256) x cols [512q, 512q+512). Each thread
// owns one row's 8-word (64B) segment — accumulated in registers, stored as one
// contiguous full cache line (kills the 4x partial-line write amplification
// seen in R8's word-scatter layout). 512 col boxes + areas staged in LDS.
// Fully-lower segments skipped (stay poison — never read, same invariant);
// boundary-segment sub-diagonal words now computed as zeros (strictly safer).
// Division removed bit-exactly: RN(a/u) > 0.5  <=>  a*2^25 - u*2^24 - u > 0.
__global__ __launch_bounds__(256) void mask_kernel(
    const float4* __restrict__ boxes, u64* __restrict__ mask) {
  int q = blockIdx.x;   // col panel
  int ry = blockIdx.y;  // row block
  if ((q + 1) * PANW <= ry * 256) return;  // whole block strictly lower-tri
  __shared__ float4 cbox[PANW];
  __shared__ float carea[PANW];
  int tid = threadIdx.x;
  int jbase = q * PANW;
  for (int t = tid; t < PANW; t += 256) {
    float4 b = boxes[jbase + t];
    cbox[t] = b;
    carea[t] = fmaxf(b.z - b.x, 0.0f) * fmaxf(b.w - b.y, 0.0f);
  }
  __syncthreads();
  int r = ry * 256 + tid;
  if (jbase + PANW <= r) return;  // whole segment lower-tri (no barrier after)
  float4 bi = boxes[r];
  float areaA = fmaxf(bi.z - bi.x, 0.0f) * fmaxf(bi.w - bi.y, 0.0f);
  int rel = r - jbase;  // bit cc set only if cc > rel
  u64 out[8];
#pragma unroll
  for (int w = 0; w < 8; ++w) {
    u64 bits = 0ull;
#pragma unroll 8
    for (int c = 0; c < 64; ++c) {
      int cc = (w << 6) + c;
      float4 bj = cbox[cc];
      float lxv = fmaxf(bi.x, bj.x), lyv = fmaxf(bi.y, bj.y);
      float rxv = fminf(bi.z, bj.z), ryv = fminf(bi.w, bj.w);
      float iw = fmaxf(rxv - lxv, 0.0f), ih = fmaxf(ryv - lyv, 0.0f);
      float inter = iw * ih;
      float u = areaA + carea[cc] - inter + 1e-8f;
      float sA = inter * 33554432.0f;  // * 2^25, exact
      float sB = u * 16777216.0f;      // * 2^24, exact
      bool sup = ((sA - sB) - u > 0.0f) & (cc > rel);
      bits |= ((u64)sup) << c;
    }
    out[w] = bits;
  }
  ulonglong2* dst = (ulonglong2*)(mask + (size_t)r * 128 + q * 8);
  dst[0] = make_ulonglong2(out[0], out[1]);
  dst[1] = make_ulonglong2(out[2], out[3]);
  dst[2] = make_ulonglong2(out[4], out[5]);
  dst[3] = make_ulonglong2(out[6], out[7]);
}

// ---------------- K4: serial greedy scan (R6 proven form) ----------------
// No VM ops inside the scan loop (R5/R7 lesson). Panel words in named regs
// rv0..rv7; 2-way speculative keeps.
__global__ __launch_bounds__(64) void nms_scan_kernel(
    const u64* __restrict__ mask, int* __restrict__ kept, int* __restrict__ num_kept) {
  __shared__ u64 slab[2][PANW * 8];  // 2 x 32 KiB double-buffered diagonal slabs
  __shared__ int keptLi[PAD];        // in-panel indices, indexed by global cnt
  int lane = threadIdx.x;
  u64 own0 = 0ull, own1 = 0ull;      // lane owns global remv words 2l, 2l+1
  int cnt = 0;
  const char* mb = (const char*)mask;

  // slab copy for panel 0: rows [0,512) x words [0,8)
#pragma unroll
  for (int it = 0; it < 32; ++it) {
    const char* g = mb + (size_t)(it * 16 + (lane >> 2)) * 1024 + (lane & 3) * 16;
    __builtin_amdgcn_global_load_lds(
        (const __attribute__((address_space(1))) unsigned int*)g,
        (__attribute__((address_space(3))) unsigned int*)(&slab[0][0] + it * 128), 16, 0, 0);
  }

  for (int p = 0; p < NPANEL; ++p) {
    int base = p * PANW;
    const u64* sl = &slab[p & 1][0];
    __syncthreads();  // drains slab copy (vmcnt0) — no VM ops live during scan

    // panel entry: replicate remv words 8p..8p+7 into named regs
    u64 rv0 = __shfl(own0, 4 * p), rv1 = __shfl(own1, 4 * p);
    u64 rv2 = __shfl(own0, 4 * p + 1), rv3 = __shfl(own1, 4 * p + 1);
    u64 rv4 = __shfl(own0, 4 * p + 2), rv5 = __shfl(own1, 4 * p + 2);
    u64 rv6 = __shfl(own0, 4 * p + 3), rv7 = __shfl(own1, 4 * p + 3);
    int w = 0;
    u64 cur = rv0;
    int panelFirst = cnt;

    while (cnt < PAD) {
      u64 inv = ~cur;
      if (inv == 0ull) {  // word exhausted
        if (++w == 8) break;
        cur = (w == 1) ? rv1 : (w == 2) ? rv2 : (w == 3) ? rv3 : (w == 4) ? rv4
            : (w == 5) ? rv5 : (w == 6) ? rv6 : rv7;
        continue;
      }
      int b1 = __ffsll(inv) - 1;
      u64 inv2 = inv & (inv - 1);
      int li1 = (w << 6) + b1;
      int b2 = inv2 ? (__ffsll(inv2) - 1) : -1;
      int li2 = inv2 ? ((w << 6) + b2) : li1;
      const u64* rA = sl + li1 * 8;
      const u64* rB = sl + li2 * 8;
      u64 mA = rA[w];  // dependent hop (chain)
      u64 mB = rB[w];  // speculative, same latency window
      ulonglong2 a0 = ((const ulonglong2*)rA)[0], a1 = ((const ulonglong2*)rA)[1];
      ulonglong2 a2 = ((const ulonglong2*)rA)[2], a3 = ((const ulonglong2*)rA)[3];
      if (lane == 0) kept[cnt] = base + li1;
      keptLi[cnt] = li1;
      cnt++;
      cur |= mA | (1ull << b1);
      rv0 |= a0.x; rv1 |= a0.y; rv2 |= a1.x; rv3 |= a1.y;
      rv4 |= a2.x; rv5 |= a2.y; rv6 |= a3.x; rv7 |= a3.y;
      if (b2 >= 0 && cnt < PAD && !((mA >> b2) & 1ull)) {  // speculation success
        ulonglong2 c0 = ((const ulonglong2*)rB)[0], c1 = ((const ulonglong2*)rB)[1];
        ulonglong2 c2 = ((const ulonglong2*)rB)[2], c3 = ((const ulonglong2*)rB)[3];
        if (lane == 0) kept[cnt] = base + li2;
        keptLi[cnt] = li2;
        cnt++;
        cur |= mB | (1ull << b2);
        rv0 |= c0.x; rv1 |= c0.y; rv2 |= c1.x; rv3 |= c1.y;
        rv4 |= c2.x; rv5 |= c2.y; rv6 |= c3.x; rv7 |= c3.y;
      }
    }
    if (cnt >= PAD || p == NPANEL - 1) break;

    // issue slab copy for panel p+1 (overlaps the fold below; drained at top barrier)
    {
      u64* dst = &slab[(p + 1) & 1][0];
      const char* srcB = mb + (size_t)(base + PANW) * 1024 + (size_t)(p + 1) * 64;
#pragma unroll
      for (int it = 0; it < 32; ++it) {
        const char* g = srcB + (size_t)(it * 16 + (lane >> 2)) * 1024 + (lane & 3) * 16;
        __builtin_amdgcn_global_load_lds(
            (const __attribute__((address_space(1))) unsigned int*)g,
            (__attribute__((address_space(3))) unsigned int*)(dst + it * 128), 16, 0, 0);
      }
    }

    // panel-exit fold: OR this panel's keeps' FULL 1KB rows into owned words.
    int nk = cnt - panelFirst;
    for (int t0 = 0; t0 < nk; t0 += 8) {
      int m = nk - t0;
      ulonglong2 v0, v1, v2, v3, v4, v5, v6, v7;
#define ROWP(t) (((const ulonglong2*)(mask + (size_t)(base + keptLi[panelFirst + (t)]) * 128))[lane])
      if (0 < m) v0 = ROWP(t0 + 0);
      if (1 < m) v1 = ROWP(t0 + 1);
      if (2 < m) v2 = ROWP(t0 + 2);
      if (3 < m) v3 = ROWP(t0 + 3);
      if (4 < m) v4 = ROWP(t0 + 4);
      if (5 < m) v5 = ROWP(t0 + 5);
      if (6 < m) v6 = ROWP(t0 + 6);
      if (7 < m) v7 = ROWP(t0 + 7);
#undef ROWP
      if (0 < m) { own0 |= v0.x; own1 |= v0.y; }
      if (1 < m) { own0 |= v1.x; own1 |= v1.y; }
      if (2 < m) { own0 |= v2.x; own1 |= v2.y; }
      if (3 < m) { own0 |= v3.x; own1 |= v3.y; }
      if (4 < m) { own0 |= v4.x; own1 |= v4.y; }
      if (5 < m) { own0 |= v5.x; own1 |= v5.y; }
      if (6 < m) { own0 |= v6.x; own1 |= v6.y; }
      if (7 < m) { own0 |= v7.x; own1 |= v7.y; }
    }
  }
  if (lane == 0) *num_kept = cnt;
}

// ---------------- K5: gather outputs ----------------
__global__ __launch_bounds__(128) void gather_kernel(
    const int* __restrict__ kept, const int* __restrict__ num_kept_p,
    const int* __restrict__ sortedIdx, const float4* __restrict__ sortedBoxes,
    const float* __restrict__ scores, float* __restrict__ out) {
  int r = blockIdx.x;  // 0..299
  int t = threadIdx.x;
  float* boxes_out = out;             // (300,4)
  float* scores_out = out + PAD * 4;  // (300,81)
  int nk = *num_kept_p;
  bool valid = r < nk;
  int pos = valid ? kept[r] : 0;
  if (t < NCLS) {
    int orig = sortedIdx[pos];
    scores_out[(size_t)r * NCLS + t] = valid ? scores[(size_t)orig * NCLS + t] : 0.0f;
  }
  if (t == 96) {
    float4 b = sortedBoxes[pos];
    if (!valid) b = make_float4(0.f, 0.f, 0.f, 0.f);
    ((float4*)boxes_out)[r] = b;
  }
}

extern "C" void kernel_launch(void* const* d_in, const int* in_sizes, int n_in,
                              void* d_out, int out_size, void* d_ws, size_t ws_size,
                              hipStream_t stream) {
  const float* meta = (const float*)d_in[0];
  const float* deltas = (const float*)d_in[1];
  const float* proposals = (const float*)d_in[2];
  const float* scores = (const float*)d_in[3];
  float* out = (float*)d_out;
  char* ws = (char*)d_ws;

  float4* sel = (float4*)(ws + 0);               // 131072 B
  u64* keys = (u64*)(ws + 131072);               // 65536 B
  int* rank = (int*)(ws + 196608);               // 32768 B
  int* sortedIdx = (int*)(ws + 229376);          // 32768 B
  float4* sortedBoxes = (float4*)(ws + 262144);  // 131072 B
  int* kept = (int*)(ws + 393216);               // 1200 B
  int* num_kept = (int*)(ws + 395264);           // 4 B
  u64* mask = (u64*)(ws + 409600);               // 8 MiB row-major

  decode_kernel<<<N / 32, 256, 0, stream>>>(meta, deltas, proposals, scores, sel, keys, rank);
  rank_kernel<<<dim3(N / 256, N / 256), 256, 0, stream>>>(keys, rank);
  scatter_kernel<<<N / 256, 256, 0, stream>>>(rank, sel, sortedIdx, sortedBoxes);
  mask_kernel<<<dim3(N / PANW, N / 256), 256, 0, stream>>>(sortedBoxes, mask);
  nms_scan_kernel<<<1, 64, 0, stream>>>(mask, kept, num_kept);
  gather_kernel<<<PAD, 128, 0, stream>>>(kept, num_kept, sortedIdx, sortedBoxes, scores, out);
}

// Round 11
// 116.431 us; speedup vs baseline: 1.7076x; 1.0215x over previous
//
#include <hip/hip_runtime.h>

#define N 8192
#define NCLS 81
#define PAD 300
#define NPANEL 16
#define PANW 512

typedef unsigned long long u64;

// ---------------- K1: decode, 8 lanes per row (coalesced 32B segments) ----------------
__global__ __launch_bounds__(256) void decode_kernel(
    const float* __restrict__ meta, const float* __restrict__ deltas,
    const float* __restrict__ proposals, const float* __restrict__ scores,
    float4* __restrict__ sel, u64* __restrict__ keys, int* __restrict__ rank) {
  int tid = threadIdx.x;
  int row = blockIdx.x * 32 + (tid >> 3);
  int sub = tid & 7;
  const float* srow = scores + (size_t)row * NCLS;
  float bs = -1e30f, ms = -1e30f;
  int best = 0;
  for (int c = sub; c < NCLS; c += 8) {
    float v = srow[c];
    if (v > bs) { bs = v; best = c; }  // ascending c: local first-max
    if (c > 0) ms = fmaxf(ms, v);
  }
  // 8-lane reduce: (max val, min class idx on ties) == global first-max (jnp.argmax)
#pragma unroll
  for (int d = 1; d < 8; d <<= 1) {
    float ob = __shfl_xor(bs, d);
    int oi = __shfl_xor(best, d);
    float om = __shfl_xor(ms, d);
    if (ob > bs || (ob == bs && oi < best)) { bs = ob; best = oi; }
    ms = fmaxf(ms, om);
  }
  if (sub == 0) {
    float W = meta[1], sc = meta[2], H = meta[0];
    const float* p = proposals + row * 4;
    float x1 = p[0] / sc, y1 = p[1] / sc, x2 = p[2] / sc, y2 = p[3] / sc;
    float w = x2 - x1 + 1.0f, h = y2 - y1 + 1.0f;
    float cx = x1 + 0.5f * w, cy = y1 + 0.5f * h;
    float4 d4 = *(const float4*)(deltas + (size_t)row * (4 * NCLS) + best * 4);  // 16B aligned
    float pcx = d4.x * w + cx, pcy = d4.y * h + cy;
    float pw = expf(d4.z) * w, ph = expf(d4.w) * h;
    float lx = W - 1.0f, ly = H - 1.0f;
    float ox1 = fminf(fmaxf(pcx - 0.5f * pw, 0.0f), lx);
    float oy1 = fminf(fmaxf(pcy - 0.5f * ph, 0.0f), ly);
    float ox2 = fminf(fmaxf(pcx + 0.5f * pw, 0.0f), lx);
    float oy2 = fminf(fmaxf(pcy + 0.5f * ph, 0.0f), ly);
    sel[row] = make_float4(ox1, oy1, ox2, oy2);
    keys[row] = ((u64)(~__float_as_uint(ms)) << 32) | (unsigned)row;
    rank[row] = 0;
  }
}

// ---------------- K2a: brute-force rank, LDS-tiled (stable sort of unique keys) ------
__global__ __launch_bounds__(256) void rank_kernel(
    const u64* __restrict__ keys, int* __restrict__ rank) {
  __shared__ u64 kt[256];
  int tid = threadIdx.x;
  int i = blockIdx.x * 256 + tid;
  kt[tid] = keys[blockIdx.y * 256 + tid];
  u64 ki = keys[i];
  __syncthreads();
  int c = 0;
#pragma unroll 8
  for (int t = 0; t < 256; ++t) c += (kt[t] < ki);
  atomicAdd(&rank[i], c);
}

// ---------------- K2b: scatter into sorted order ----------------
__global__ __launch_bounds__(256) void scatter_kernel(
    const int* __restrict__ rank, const float4* __restrict__ sel,
    int* __restrict__ sortedIdx, float4* __restrict__ sortedBoxes) {
  int i = blockIdx.x * 256 + threadIdx.x;
  int r = rank[i];
  sortedIdx[r] = i;
  sortedBoxes[r] = sel[i];
}

// ---------------- K3: suppression bitmask — occupancy-first tiling ----------------
// Block (q, ry): rows [256ry, +256) x cols [128q, +128). Thread = 1 row x 128
// cols -> 2 output words (16B store). Grid (64,32): 1056 active blocks ~ 4.1
// waves/SIMD (R9 had 1/SIMD and ran at ~20% VALU issue — latency-bound).
// 16B partial-line stores cost 2-4x write amp; R8 measured that as non-binding.
// Poison invariant unchanged: strictly-lower words (skipped threads/blocks) are
// never read by the scan; diagonal words get computed zeros via per-word mask.
// FP expression order identical to R9 (absmax-0-proven); division removed
// bit-exactly: RN(a/u) > 0.5  <=>  a*2^25 - u*2^24 - u > 0.
__global__ __launch_bounds__(256) void mask_kernel(
    const float4* __restrict__ boxes, u64* __restrict__ mask) {
  int q = blockIdx.x;   // col-group of 128
  int ry = blockIdx.y;  // row-group of 256
  int jbase = q * 128, rbase = ry * 256;
  if (jbase + 128 <= rbase) return;  // strictly lower-tri block
  __shared__ float4 cbox[128];
  __shared__ float carea[128];
  int tid = threadIdx.x;
  if (tid < 128) {
    float4 b = boxes[jbase + tid];
    cbox[tid] = b;
    carea[tid] = fmaxf(b.z - b.x, 0.0f) * fmaxf(b.w - b.y, 0.0f);
  }
  __syncthreads();
  int r = rbase + tid;
  int rel = r - jbase;      // bits valid only for cc > rel
  if (rel >= 128) return;   // both words strictly lower-tri: stay poison (never read)
  float4 bi = boxes[r];
  float areaA = fmaxf(bi.z - bi.x, 0.0f) * fmaxf(bi.w - bi.y, 0.0f);
  u64 out2[2];
#pragma unroll
  for (int w = 0; w < 2; ++w) {
    unsigned lo = 0, hi = 0;
#pragma unroll 16
    for (int c = 0; c < 64; ++c) {
      int cc = (w << 6) + c;
      float4 bj = cbox[cc];
      float lxv = fmaxf(bi.x, bj.x), lyv = fmaxf(bi.y, bj.y);
      float rxv = fminf(bi.z, bj.z), ryv = fminf(bi.w, bj.w);
      float iw = fmaxf(rxv - lxv, 0.0f), ih = fmaxf(ryv - lyv, 0.0f);
      float inter = iw * ih;
      float u = areaA + carea[cc] - inter + 1e-8f;  // exact ref assoc order
      float sA = inter * 33554432.0f;  // * 2^25, exact
      float sB = u * 16777216.0f;      // * 2^24, exact
      unsigned sup = (((sA - sB) - u) > 0.0f) ? 1u : 0u;
      if (c < 32) lo |= sup << c; else hi |= sup << (c - 32);
    }
    u64 bits = ((u64)hi << 32) | lo;
    int relw = rel - (w << 6);            // need c > relw within this word
    if (relw >= 63) bits = 0ull;
    else if (relw >= 0) bits &= ~((1ull << (relw + 1)) - 1ull);
    out2[w] = bits;
  }
  *(ulonglong2*)(mask + (size_t)r * 128 + q * 2) = make_ulonglong2(out2[0], out2[1]);
}

// ---------------- K4: serial greedy scan (R6 proven form) ----------------
// No VM ops inside the scan loop (R5/R7 lesson). Panel words in named regs
// rv0..rv7; 2-way speculative keeps.
__global__ __launch_bounds__(64) void nms_scan_kernel(
    const u64* __restrict__ mask, int* __restrict__ kept, int* __restrict__ num_kept) {
  __shared__ u64 slab[2][PANW * 8];  // 2 x 32 KiB double-buffered diagonal slabs
  __shared__ int keptLi[PAD];        // in-panel indices, indexed by global cnt
  int lane = threadIdx.x;
  u64 own0 = 0ull, own1 = 0ull;      // lane owns global remv words 2l, 2l+1
  int cnt = 0;
  const char* mb = (const char*)mask;

  // slab copy for panel 0: rows [0,512) x words [0,8)
#pragma unroll
  for (int it = 0; it < 32; ++it) {
    const char* g = mb + (size_t)(it * 16 + (lane >> 2)) * 1024 + (lane & 3) * 16;
    __builtin_amdgcn_global_load_lds(
        (const __attribute__((address_space(1))) unsigned int*)g,
        (__attribute__((address_space(3))) unsigned int*)(&slab[0][0] + it * 128), 16, 0, 0);
  }

  for (int p = 0; p < NPANEL; ++p) {
    int base = p * PANW;
    const u64* sl = &slab[p & 1][0];
    __syncthreads();  // drains slab copy (vmcnt0) — no VM ops live during scan

    // panel entry: replicate remv words 8p..8p+7 into named regs
    u64 rv0 = __shfl(own0, 4 * p), rv1 = __shfl(own1, 4 * p);
    u64 rv2 = __shfl(own0, 4 * p + 1), rv3 = __shfl(own1, 4 * p + 1);
    u64 rv4 = __shfl(own0, 4 * p + 2), rv5 = __shfl(own1, 4 * p + 2);
    u64 rv6 = __shfl(own0, 4 * p + 3), rv7 = __shfl(own1, 4 * p + 3);
    int w = 0;
    u64 cur = rv0;
    int panelFirst = cnt;

    while (cnt < PAD) {
      u64 inv = ~cur;
      if (inv == 0ull) {  // word exhausted
        if (++w == 8) break;
        cur = (w == 1) ? rv1 : (w == 2) ? rv2 : (w == 3) ? rv3 : (w == 4) ? rv4
            : (w == 5) ? rv5 : (w == 6) ? rv6 : rv7;
        continue;
      }
      int b1 = __ffsll(inv) - 1;
      u64 inv2 = inv & (inv - 1);
      int li1 = (w << 6) + b1;
      int b2 = inv2 ? (__ffsll(inv2) - 1) : -1;
      int li2 = inv2 ? ((w << 6) + b2) : li1;
      const u64* rA = sl + li1 * 8;
      const u64* rB = sl + li2 * 8;
      u64 mA = rA[w];  // dependent hop (chain)
      u64 mB = rB[w];  // speculative, same latency window
      ulonglong2 a0 = ((const ulonglong2*)rA)[0], a1 = ((const ulonglong2*)rA)[1];
      ulonglong2 a2 = ((const ulonglong2*)rA)[2], a3 = ((const ulonglong2*)rA)[3];
      if (lane == 0) kept[cnt] = base + li1;
      keptLi[cnt] = li1;
      cnt++;
      cur |= mA | (1ull << b1);
      rv0 |= a0.x; rv1 |= a0.y; rv2 |= a1.x; rv3 |= a1.y;
      rv4 |= a2.x; rv5 |= a2.y; rv6 |= a3.x; rv7 |= a3.y;
      if (b2 >= 0 && cnt < PAD && !((mA >> b2) & 1ull)) {  // speculation success
        ulonglong2 c0 = ((const ulonglong2*)rB)[0], c1 = ((const ulonglong2*)rB)[1];
        ulonglong2 c2 = ((const ulonglong2*)rB)[2], c3 = ((const ulonglong2*)rB)[3];
        if (lane == 0) kept[cnt] = base + li2;
        keptLi[cnt] = li2;
        cnt++;
        cur |= mB | (1ull << b2);
        rv0 |= c0.x; rv1 |= c0.y; rv2 |= c1.x; rv3 |= c1.y;
        rv4 |= c2.x; rv5 |= c2.y; rv6 |= c3.x; rv7 |= c3.y;
      }
    }
    if (cnt >= PAD || p == NPANEL - 1) break;

    // issue slab copy for panel p+1 (overlaps the fold below; drained at top barrier)
    {
      u64* dst = &slab[(p + 1) & 1][0];
      const char* srcB = mb + (size_t)(base + PANW) * 1024 + (size_t)(p + 1) * 64;
#pragma unroll
      for (int it = 0; it < 32; ++it) {
        const char* g = srcB + (size_t)(it * 16 + (lane >> 2)) * 1024 + (lane & 3) * 16;
        __builtin_amdgcn_global_load_lds(
            (const __attribute__((address_space(1))) unsigned int*)g,
            (__attribute__((address_space(3))) unsigned int*)(dst + it * 128), 16, 0, 0);
      }
    }

    // panel-exit fold: OR this panel's keeps' FULL 1KB rows into owned words.
    int nk = cnt - panelFirst;
    for (int t0 = 0; t0 < nk; t0 += 8) {
      int m = nk - t0;
      ulonglong2 v0, v1, v2, v3, v4, v5, v6, v7;
#define ROWP(t) (((const ulonglong2*)(mask + (size_t)(base + keptLi[panelFirst + (t)]) * 128))[lane])
      if (0 < m) v0 = ROWP(t0 + 0);
      if (1 < m) v1 = ROWP(t0 + 1);
      if (2 < m) v2 = ROWP(t0 + 2);
      if (3 < m) v3 = ROWP(t0 + 3);
      if (4 < m) v4 = ROWP(t0 + 4);
      if (5 < m) v5 = ROWP(t0 + 5);
      if (6 < m) v6 = ROWP(t0 + 6);
      if (7 < m) v7 = ROWP(t0 + 7);
#undef ROWP
      if (0 < m) { own0 |= v0.x; own1 |= v0.y; }
      if (1 < m) { own0 |= v1.x; own1 |= v1.y; }
      if (2 < m) { own0 |= v2.x; own1 |= v2.y; }
      if (3 < m) { own0 |= v3.x; own1 |= v3.y; }
      if (4 < m) { own0 |= v4.x; own1 |= v4.y; }
      if (5 < m) { own0 |= v5.x; own1 |= v5.y; }
      if (6 < m) { own0 |= v6.x; own1 |= v6.y; }
      if (7 < m) { own0 |= v7.x; own1 |= v7.y; }
    }
  }
  if (lane == 0) *num_kept = cnt;
}

// ---------------- K5: gather outputs ----------------
__global__ __launch_bounds__(128) void gather_kernel(
    const int* __restrict__ kept, const int* __restrict__ num_kept_p,
    const int* __restrict__ sortedIdx, const float4* __restrict__ sortedBoxes,
    const float* __restrict__ scores, float* __restrict__ out) {
  int r = blockIdx.x;  // 0..299
  int t = threadIdx.x;
  float* boxes_out = out;             // (300,4)
  float* scores_out = out + PAD * 4;  // (300,81)
  int nk = *num_kept_p;
  bool valid = r < nk;
  int pos = valid ? kept[r] : 0;
  if (t < NCLS) {
    int orig = sortedIdx[pos];
    scores_out[(size_t)r * NCLS + t] = valid ? scores[(size_t)orig * NCLS + t] : 0.0f;
  }
  if (t == 96) {
    float4 b = sortedBoxes[pos];
    if (!valid) b = make_float4(0.f, 0.f, 0.f, 0.f);
    ((float4*)boxes_out)[r] = b;
  }
}

extern "C" void kernel_launch(void* const* d_in, const int* in_sizes, int n_in,
                              void* d_out, int out_size, void* d_ws, size_t ws_size,
                              hipStream_t stream) {
  const float* meta = (const float*)d_in[0];
  const float* deltas = (const float*)d_in[1];
  const float* proposals = (const float*)d_in[2];
  const float* scores = (const float*)d_in[3];
  float* out = (float*)d_out;
  char* ws = (char*)d_ws;

  float4* sel = (float4*)(ws + 0);               // 131072 B
  u64* keys = (u64*)(ws + 131072);               // 65536 B
  int* rank = (int*)(ws + 196608);               // 32768 B
  int* sortedIdx = (int*)(ws + 229376);          // 32768 B
  float4* sortedBoxes = (float4*)(ws + 262144);  // 131072 B
  int* kept = (int*)(ws + 393216);               // 1200 B
  int* num_kept = (int*)(ws + 395264);           // 4 B
  u64* mask = (u64*)(ws + 409600);               // 8 MiB row-major

  decode_kernel<<<N / 32, 256, 0, stream>>>(meta, deltas, proposals, scores, sel, keys, rank);
  rank_kernel<<<dim3(N / 256, N / 256), 256, 0, stream>>>(keys, rank);
  scatter_kernel<<<N / 256, 256, 0, stream>>>(rank, sel, sortedIdx, sortedBoxes);
  mask_kernel<<<dim3(N / 128, N / 256), 256, 0, stream>>>(sortedBoxes, mask);
  nms_scan_kernel<<<1, 64, 0, stream>>>(mask, kept, num_kept);
  gather_kernel<<<PAD, 128, 0, stream>>>(kept, num_kept, sortedIdx, sortedBoxes, scores, out);
}